// Round 1
// baseline (999.663 us; speedup 1.0000x reference)
//
#include <hip/hip_runtime.h>

#define N_NODES 100000
#define N_EDGES 3200000
#define ROWS_PAD 100032   // multiple of 64 for GEMM tiling
#define C_DIM 128

typedef __attribute__((ext_vector_type(8))) short bf16x8;
typedef __attribute__((ext_vector_type(4))) float f32x4;

__device__ __forceinline__ unsigned short f2bf(float f) {
    unsigned u = __float_as_uint(f);
    unsigned r = (u + 0x7fffu + ((u >> 16) & 1u)) >> 16;  // round-to-nearest-even
    return (unsigned short)r;
}
__device__ __forceinline__ float bflo(unsigned u) { return __uint_as_float(u << 16); }
__device__ __forceinline__ float bfhi(unsigned u) { return __uint_as_float(u & 0xffff0000u); }

// ---- convert x (fp32 [N,128]) -> bf16 [ROWS_PAD,128], zero-padded tail rows ----
__global__ void k_convert_x(const float* __restrict__ x, unsigned short* __restrict__ xb) {
    int i = blockIdx.x * 256 + threadIdx.x;          // grid covers ROWS_PAD*128 exactly
    int r = i >> 7;
    float v = (r < N_NODES) ? x[i] : 0.0f;
    xb[i] = f2bf(v);
}

// ---- convert+transpose W [4][k][c] fp32 -> WT [4][c][k] bf16 ----
__global__ void k_convert_w(const float* __restrict__ w, unsigned short* __restrict__ wt) {
    int i = blockIdx.x * 256 + threadIdx.x;          // 65536 total
    int m = i >> 14, rem = i & 16383, k = rem >> 7, c = rem & 127;
    wt[(m << 14) + (c << 7) + k] = f2bf(w[i]);
}

// ---- CSR build ----
__global__ void k_hist(const int* __restrict__ ei, int* __restrict__ counts) {
    int e = blockIdx.x * 256 + threadIdx.x;
    if (e < N_EDGES) atomicAdd(&counts[ei[e]], 1);
}

__global__ void k_scan1(const int* __restrict__ counts, int* __restrict__ rowstart,
                        int* __restrict__ bsums, int n) {
    __shared__ int s[1024];
    int i = blockIdx.x * 1024 + threadIdx.x;
    int v = (i < n) ? counts[i] : 0;
    s[threadIdx.x] = v;
    __syncthreads();
    for (int off = 1; off < 1024; off <<= 1) {
        int t = (threadIdx.x >= off) ? s[threadIdx.x - off] : 0;
        __syncthreads();
        s[threadIdx.x] += t;
        __syncthreads();
    }
    if (i < n) rowstart[i] = s[threadIdx.x] - v;      // exclusive
    if (threadIdx.x == 1023) bsums[blockIdx.x] = s[1023];
}

__global__ void k_scan2(int* __restrict__ bsums, int nb) {
    __shared__ int s[128];
    int v = (threadIdx.x < nb) ? bsums[threadIdx.x] : 0;
    s[threadIdx.x] = v;
    __syncthreads();
    for (int off = 1; off < 128; off <<= 1) {
        int t = (threadIdx.x >= off) ? s[threadIdx.x - off] : 0;
        __syncthreads();
        s[threadIdx.x] += t;
        __syncthreads();
    }
    if (threadIdx.x < nb) bsums[threadIdx.x] = s[threadIdx.x] - v;  // exclusive
}

__global__ void k_scan3(int* __restrict__ rowstart, const int* __restrict__ bsums,
                        int* __restrict__ cursor, int n) {
    int i = blockIdx.x * 256 + threadIdx.x;
    if (i < n) {
        int v = rowstart[i] + bsums[i >> 10];
        rowstart[i] = v;
        if (i < N_NODES) cursor[i] = v;
    }
}

__global__ void k_permute(const int* __restrict__ ei, const float* __restrict__ lap,
                          int* __restrict__ cursor, int2* __restrict__ ep) {
    int e = blockIdx.x * 256 + threadIdx.x;
    if (e < N_EDGES) {
        int row = ei[e], col = ei[N_EDGES + e];
        int p = atomicAdd(&cursor[row], 1);
        ep[p] = make_int2(col, __float_as_int(lap[e]));
    }
}

// ---- SpMM gather: y[r] = a * sum_e lap_e * xs[col_e]  +  b * z[r]   (all bf16, fp32 acc)
// one wave per row, 2 channels per lane
__global__ void __launch_bounds__(256) k_spmm(
    const unsigned short* __restrict__ xs, const unsigned short* __restrict__ z,
    unsigned short* __restrict__ y, const int* __restrict__ rowstart,
    const int2* __restrict__ ep, float a, float b)
{
    int wv = threadIdx.x >> 6, lane = threadIdx.x & 63;
    int r = blockIdx.x * 4 + wv;                     // grid = ROWS_PAD/4
    if (r < N_NODES) {
        float acc0 = 0.f, acc1 = 0.f;
        int e0 = rowstart[r], e1 = rowstart[r + 1];
        int e = e0;
        for (; e + 4 <= e1; e += 4) {
            int2 p0 = ep[e], p1 = ep[e + 1], p2 = ep[e + 2], p3 = ep[e + 3];
            unsigned g0 = *(const unsigned*)(xs + p0.x * 128 + 2 * lane);
            unsigned g1 = *(const unsigned*)(xs + p1.x * 128 + 2 * lane);
            unsigned g2 = *(const unsigned*)(xs + p2.x * 128 + 2 * lane);
            unsigned g3 = *(const unsigned*)(xs + p3.x * 128 + 2 * lane);
            float l0 = __int_as_float(p0.y), l1 = __int_as_float(p1.y);
            float l2 = __int_as_float(p2.y), l3 = __int_as_float(p3.y);
            acc0 += l0 * bflo(g0); acc1 += l0 * bfhi(g0);
            acc0 += l1 * bflo(g1); acc1 += l1 * bfhi(g1);
            acc0 += l2 * bflo(g2); acc1 += l2 * bfhi(g2);
            acc0 += l3 * bflo(g3); acc1 += l3 * bfhi(g3);
        }
        for (; e < e1; ++e) {
            int2 p = ep[e];
            unsigned g = *(const unsigned*)(xs + p.x * 128 + 2 * lane);
            float l = __int_as_float(p.y);
            acc0 += l * bflo(g); acc1 += l * bfhi(g);
        }
        unsigned zg = *(const unsigned*)(z + r * 128 + 2 * lane);   // read BEFORE write (in-place safe)
        float o0 = a * acc0 + b * bflo(zg);
        float o1 = a * acc1 + b * bfhi(zg);
        *(unsigned*)(y + r * 128 + 2 * lane) =
            (unsigned)f2bf(o0) | ((unsigned)f2bf(o1) << 16);
    } else {
        *(unsigned*)(y + r * 128 + 2 * lane) = 0u;   // pad rows stay zero
    }
}

// ---- MFMA GEMM: out[N,128] (fp32) (+)= A[ROWS_PAD,128](bf16) @ W (via WT[c][k] bf16)
// mode 0: write, 1: accumulate, 2: accumulate + bias
__global__ void __launch_bounds__(256) k_gemm(
    const unsigned short* __restrict__ A, const unsigned short* __restrict__ WT,
    float* __restrict__ out, const float* __restrict__ bias, int mode)
{
    int wv = threadIdx.x >> 6, lane = threadIdx.x & 63;
    int m = lane & 15, quad = lane >> 4;
    int r0 = blockIdx.x * 64 + wv * 16;
    bf16x8 afrag[4];
    const short* Ap = (const short*)A + (r0 + m) * 128 + quad * 8;
#pragma unroll
    for (int kk = 0; kk < 4; ++kk) afrag[kk] = *(const bf16x8*)(Ap + kk * 32);
#pragma unroll
    for (int ct = 0; ct < 8; ++ct) {
        int c0 = ct * 16;
        const short* Bp = (const short*)WT + (c0 + m) * 128 + quad * 8;
        f32x4 acc = {0.f, 0.f, 0.f, 0.f};
#pragma unroll
        for (int kk = 0; kk < 4; ++kk) {
            bf16x8 bfrag = *(const bf16x8*)(Bp + kk * 32);
            acc = __builtin_amdgcn_mfma_f32_16x16x32_bf16(afrag[kk], bfrag, acc, 0, 0, 0);
        }
        int c = c0 + m;                               // C/D layout: col=lane&15, row=quad*4+i
#pragma unroll
        for (int i = 0; i < 4; ++i) {
            int r = r0 + quad * 4 + i;
            if (r < N_NODES) {
                float* o = out + (size_t)r * 128 + c;
                if (mode == 0)      *o = acc[i];
                else if (mode == 1) *o += acc[i];
                else                *o = *o + acc[i] + bias[c];
            }
        }
    }
}

extern "C" void kernel_launch(void* const* d_in, const int* in_sizes, int n_in,
                              void* d_out, int out_size, void* d_ws, size_t ws_size,
                              hipStream_t stream) {
    const float* x    = (const float*)d_in[0];
    const float* lap  = (const float*)d_in[1];
    const float* w    = (const float*)d_in[2];
    const float* bias = (const float*)d_in[3];
    const int*   ei   = (const int*)d_in[4];
    float* out = (float*)d_out;

    char* ws = (char*)d_ws;
    const size_t SZ_BF = (size_t)ROWS_PAD * 128 * 2;          // 25,608,192 B
    unsigned short* xb   = (unsigned short*)(ws);
    unsigned short* bufA = (unsigned short*)(ws + SZ_BF);
    unsigned short* bufB = (unsigned short*)(ws + 2 * SZ_BF);
    int2* ep = (int2*)(ws + 3 * SZ_BF);
    char* p = ws + 3 * SZ_BF + (size_t)N_EDGES * 8;
    int* rowstart = (int*)p; p += 400128;
    int* cursor   = (int*)p; p += 400128;
    int* counts   = (int*)p; p += 400128;
    int* bsums    = (int*)p; p += 512;
    unsigned short* wt = (unsigned short*)p;                   // 4*128*128 bf16

    hipMemsetAsync(counts, 0, (N_NODES + 1) * sizeof(int), stream);
    k_convert_x<<<(ROWS_PAD * 128) / 256, 256, 0, stream>>>(x, xb);
    k_convert_w<<<256, 256, 0, stream>>>(w, wt);
    k_hist<<<(N_EDGES + 255) / 256, 256, 0, stream>>>(ei, counts);
    k_scan1<<<98, 1024, 0, stream>>>(counts, rowstart, bsums, N_NODES + 1);
    k_scan2<<<1, 128, 0, stream>>>(bsums, 98);
    k_scan3<<<(N_NODES + 1 + 255) / 256, 256, 0, stream>>>(rowstart, bsums, cursor, N_NODES + 1);
    k_permute<<<(N_EDGES + 255) / 256, 256, 0, stream>>>(ei, lap, cursor, ep);

    // Tx1 = L x
    k_spmm<<<ROWS_PAD / 4, 256, 0, stream>>>(xb, xb, bufA, rowstart, ep, 1.f, 0.f);
    // out = x @ W0
    k_gemm<<<ROWS_PAD / 64, 256, 0, stream>>>(xb, wt, out, bias, 0);
    // out += Tx1 @ W1
    k_gemm<<<ROWS_PAD / 64, 256, 0, stream>>>(bufA, wt + 16384, out, bias, 1);
    // Tx2 = 2 L Tx1 - x
    k_spmm<<<ROWS_PAD / 4, 256, 0, stream>>>(bufA, xb, bufB, rowstart, ep, 2.f, -1.f);
    // out += Tx2 @ W2
    k_gemm<<<ROWS_PAD / 64, 256, 0, stream>>>(bufB, wt + 2 * 16384, out, bias, 1);
    // Tx3 = 2 L Tx2 - Tx1   (in place into bufA; per-thread read-before-write)
    k_spmm<<<ROWS_PAD / 4, 256, 0, stream>>>(bufB, bufA, bufA, rowstart, ep, 2.f, -1.f);
    // out += Tx3 @ W3 + bias
    k_gemm<<<ROWS_PAD / 64, 256, 0, stream>>>(bufA, wt + 3 * 16384, out, bias, 2);
}

// Round 2
// 745.311 us; speedup vs baseline: 1.3413x; 1.3413x over previous
//
#include <hip/hip_runtime.h>

#define N_NODES 100000
#define N_EDGES 3200000
#define ROWS_PAD 100032   // multiple of 64 for GEMM tiling
#define N_BUCKETS 782     // ceil(100000/128)
#define BUCKET_SHIFT 7

typedef __attribute__((ext_vector_type(8))) short bf16x8;
typedef __attribute__((ext_vector_type(4))) float f32x4;

__device__ __forceinline__ unsigned short f2bf(float f) {
    unsigned u = __float_as_uint(f);
    unsigned r = (u + 0x7fffu + ((u >> 16) & 1u)) >> 16;  // round-to-nearest-even
    return (unsigned short)r;
}
__device__ __forceinline__ float bflo(unsigned u) { return __uint_as_float(u << 16); }
__device__ __forceinline__ float bfhi(unsigned u) { return __uint_as_float(u & 0xffff0000u); }

// ---- convert x (fp32 [N,128]) -> bf16 [ROWS_PAD,128], zero-padded tail rows ----
__global__ void k_convert_x(const float* __restrict__ x, unsigned short* __restrict__ xb) {
    int i = blockIdx.x * 256 + threadIdx.x;
    int r = i >> 7;
    float v = (r < N_NODES) ? x[i] : 0.0f;
    xb[i] = f2bf(v);
}

// ---- convert+transpose W [4][k][c] fp32 -> WT [4][c][k] bf16 ----
__global__ void k_convert_w(const float* __restrict__ w, unsigned short* __restrict__ wt) {
    int i = blockIdx.x * 256 + threadIdx.x;          // 65536 total
    int m = i >> 14, rem = i & 16383, k = rem >> 7, c = rem & 127;
    wt[(m << 14) + (c << 7) + k] = f2bf(w[i]);
}

// ---- coarse bucket histogram (row>>7), LDS-aggregated ----
__global__ void __launch_bounds__(256) k_bhist(const int* __restrict__ ei, int* __restrict__ bcnt) {
    __shared__ int h[N_BUCKETS];
    for (int i = threadIdx.x; i < N_BUCKETS; i += 256) h[i] = 0;
    __syncthreads();
    int base = blockIdx.x * 8192;
#pragma unroll
    for (int i = 0; i < 32; ++i) {
        int e = base + threadIdx.x + i * 256;
        if (e < N_EDGES) atomicAdd(&h[ei[e] >> BUCKET_SHIFT], 1);
    }
    __syncthreads();
    for (int i = threadIdx.x; i < N_BUCKETS; i += 256)
        if (h[i]) atomicAdd(&bcnt[i], h[i]);
}

// ---- one-block exclusive scan of bucket counts ----
__global__ void __launch_bounds__(1024) k_bscan(const int* __restrict__ bcnt,
                                                int* __restrict__ bbase,
                                                int* __restrict__ bcursor,
                                                int* __restrict__ rowstart) {
    __shared__ int s[1024];
    int t = threadIdx.x;
    int v = (t < N_BUCKETS) ? bcnt[t] : 0;
    s[t] = v;
    __syncthreads();
    for (int off = 1; off < 1024; off <<= 1) {
        int tv = (t >= off) ? s[t - off] : 0;
        __syncthreads();
        s[t] += tv;
        __syncthreads();
    }
    if (t < N_BUCKETS) {
        int ex = s[t] - v;
        bbase[t] = ex;
        bcursor[t] = ex;
    }
    if (t == 0) {
        bbase[N_BUCKETS] = N_EDGES;
        rowstart[N_NODES] = N_EDGES;
    }
}

// ---- pass 1: bin edges by coarse bucket; per-block run reservation -> L2-local scatter ----
// entry: (meta = (row&127)<<17 | col, lap_bits)
__global__ void __launch_bounds__(1024) k_bin(const int* __restrict__ ei,
                                              const float* __restrict__ lap,
                                              int* __restrict__ bcursor,
                                              uint2* __restrict__ ep_tmp) {
    __shared__ int h[N_BUCKETS];
    __shared__ int runbase[N_BUCKETS];
    for (int i = threadIdx.x; i < N_BUCKETS; i += 1024) h[i] = 0;
    __syncthreads();
    int base = blockIdx.x * 16384;
#pragma unroll
    for (int i = 0; i < 16; ++i) {
        int e = base + threadIdx.x + i * 1024;
        if (e < N_EDGES) atomicAdd(&h[ei[e] >> BUCKET_SHIFT], 1);
    }
    __syncthreads();
    for (int i = threadIdx.x; i < N_BUCKETS; i += 1024) {
        int c = h[i];
        runbase[i] = c ? atomicAdd(&bcursor[i], c) : 0;
        h[i] = 0;   // reuse as local cursor
    }
    __syncthreads();
#pragma unroll
    for (int i = 0; i < 16; ++i) {
        int e = base + threadIdx.x + i * 1024;
        if (e < N_EDGES) {
            int row = ei[e], col = ei[N_EDGES + e];
            int b = row >> BUCKET_SHIFT;
            int p = runbase[b] + atomicAdd(&h[b], 1);
            ep_tmp[p] = make_uint2(((unsigned)(row & 127) << 17) | (unsigned)col,
                                   __float_as_uint(lap[e]));
        }
    }
}

// ---- pass 2: per-bucket row sort in LDS; emit rowstart + final ep ----
#define ST_CAP 5120
__global__ void __launch_bounds__(256) k_rsort(const uint2* __restrict__ ep_tmp,
                                               const int* __restrict__ bbase,
                                               int* __restrict__ rowstart,
                                               int2* __restrict__ ep) {
    __shared__ uint2 st[ST_CAP];
    __shared__ int h[128];
    __shared__ int lcur[128];
    int b = blockIdx.x;
    int base = bbase[b], end = bbase[b + 1];
    int n = end - base;
    if (n > ST_CAP) n = ST_CAP;   // statistically unreachable
    for (int i = threadIdx.x; i < n; i += 256) st[i] = ep_tmp[base + i];
    if (threadIdx.x < 128) h[threadIdx.x] = 0;
    __syncthreads();
    for (int i = threadIdx.x; i < n; i += 256) atomicAdd(&h[st[i].x >> 17], 1);
    __syncthreads();
    // exclusive scan of 128 row counts (Hillis-Steele on threads 0..127)
    int t = threadIdx.x;
    int v = (t < 128) ? h[t] : 0;
    for (int off = 1; off < 128; off <<= 1) {
        int tv = (t < 128 && t >= off) ? h[t - off] : 0;
        __syncthreads();
        if (t < 128) h[t] += tv;
        __syncthreads();
    }
    if (t < 128) {
        int ex = h[t] - v;
        int r = (b << BUCKET_SHIFT) + t;
        if (r < N_NODES) rowstart[r] = base + ex;
        lcur[t] = base + ex;
    }
    __syncthreads();
    for (int i = threadIdx.x; i < n; i += 256) {
        uint2 s = st[i];
        int r = s.x >> 17;
        int p = atomicAdd(&lcur[r], 1);
        ep[p] = make_int2((int)(s.x & 0x1FFFFu), (int)s.y);
    }
}

// ---- SpMM gather: y[r] = a * sum_e lap_e * xs[col_e]  +  b * z[r]   (bf16, fp32 acc)
__global__ void __launch_bounds__(256) k_spmm(
    const unsigned short* __restrict__ xs, const unsigned short* __restrict__ z,
    unsigned short* __restrict__ y, const int* __restrict__ rowstart,
    const int2* __restrict__ ep, float a, float b)
{
    int wv = threadIdx.x >> 6, lane = threadIdx.x & 63;
    int r = blockIdx.x * 4 + wv;
    if (r < N_NODES) {
        float acc0 = 0.f, acc1 = 0.f;
        int e0 = rowstart[r], e1 = rowstart[r + 1];
        int e = e0;
        for (; e + 8 <= e1; e += 8) {
            int2 p[8];
            unsigned g[8];
#pragma unroll
            for (int j = 0; j < 8; ++j) p[j] = ep[e + j];
#pragma unroll
            for (int j = 0; j < 8; ++j)
                g[j] = *(const unsigned*)(xs + p[j].x * 128 + 2 * lane);
#pragma unroll
            for (int j = 0; j < 8; ++j) {
                float l = __int_as_float(p[j].y);
                acc0 += l * bflo(g[j]);
                acc1 += l * bfhi(g[j]);
            }
        }
        for (; e < e1; ++e) {
            int2 p = ep[e];
            unsigned g = *(const unsigned*)(xs + p.x * 128 + 2 * lane);
            float l = __int_as_float(p.y);
            acc0 += l * bflo(g); acc1 += l * bfhi(g);
        }
        unsigned zg = *(const unsigned*)(z + r * 128 + 2 * lane);   // read BEFORE write (in-place safe)
        float o0 = a * acc0 + b * bflo(zg);
        float o1 = a * acc1 + b * bfhi(zg);
        *(unsigned*)(y + r * 128 + 2 * lane) =
            (unsigned)f2bf(o0) | ((unsigned)f2bf(o1) << 16);
    } else {
        *(unsigned*)(y + r * 128 + 2 * lane) = 0u;
    }
}

// ---- fused MFMA GEMM pair: out (+)= A0@W0 + A1@W1 (+ bias)   mode 0: write, 1: accumulate+bias
__global__ void __launch_bounds__(256) k_gemm2(
    const unsigned short* __restrict__ A0, const unsigned short* __restrict__ WT0,
    const unsigned short* __restrict__ A1, const unsigned short* __restrict__ WT1,
    float* __restrict__ out, const float* __restrict__ bias, int mode)
{
    int wv = threadIdx.x >> 6, lane = threadIdx.x & 63;
    int m = lane & 15, quad = lane >> 4;
    int r0 = blockIdx.x * 64 + wv * 16;
    bf16x8 a0[4], a1[4];
    const short* Ap0 = (const short*)A0 + (r0 + m) * 128 + quad * 8;
    const short* Ap1 = (const short*)A1 + (r0 + m) * 128 + quad * 8;
#pragma unroll
    for (int kk = 0; kk < 4; ++kk) {
        a0[kk] = *(const bf16x8*)(Ap0 + kk * 32);
        a1[kk] = *(const bf16x8*)(Ap1 + kk * 32);
    }
#pragma unroll
    for (int ct = 0; ct < 8; ++ct) {
        int c0 = ct * 16;
        const short* Bp0 = (const short*)WT0 + (c0 + m) * 128 + quad * 8;
        const short* Bp1 = (const short*)WT1 + (c0 + m) * 128 + quad * 8;
        f32x4 acc0 = {0.f, 0.f, 0.f, 0.f};
        f32x4 acc1 = {0.f, 0.f, 0.f, 0.f};
#pragma unroll
        for (int kk = 0; kk < 4; ++kk) {
            bf16x8 b0 = *(const bf16x8*)(Bp0 + kk * 32);
            bf16x8 b1 = *(const bf16x8*)(Bp1 + kk * 32);
            acc0 = __builtin_amdgcn_mfma_f32_16x16x32_bf16(a0[kk], b0, acc0, 0, 0, 0);
            acc1 = __builtin_amdgcn_mfma_f32_16x16x32_bf16(a1[kk], b1, acc1, 0, 0, 0);
        }
        int c = c0 + m;                               // C/D layout: col=lane&15, row=quad*4+i
#pragma unroll
        for (int i = 0; i < 4; ++i) {
            int r = r0 + quad * 4 + i;
            if (r < N_NODES) {
                float* o = out + (size_t)r * 128 + c;
                float v = acc0[i] + acc1[i];
                if (mode == 0) *o = v;
                else           *o = *o + v + bias[c];
            }
        }
    }
}

extern "C" void kernel_launch(void* const* d_in, const int* in_sizes, int n_in,
                              void* d_out, int out_size, void* d_ws, size_t ws_size,
                              hipStream_t stream) {
    const float* x    = (const float*)d_in[0];
    const float* lap  = (const float*)d_in[1];
    const float* w    = (const float*)d_in[2];
    const float* bias = (const float*)d_in[3];
    const int*   ei   = (const int*)d_in[4];
    float* out = (float*)d_out;

    char* ws = (char*)d_ws;
    const size_t SZ_BF = (size_t)ROWS_PAD * 128 * 2;          // 25,608,192 B
    unsigned short* xb   = (unsigned short*)(ws);
    unsigned short* bufA = (unsigned short*)(ws + SZ_BF);
    unsigned short* bufB = (unsigned short*)(ws + 2 * SZ_BF); // also aliased as ep_tmp
    uint2* ep_tmp        = (uint2*)(ws + 2 * SZ_BF);
    int2* ep             = (int2*)(ws + 3 * SZ_BF);
    char* p = ws + 4 * SZ_BF;
    int* rowstart = (int*)p; p += 400128;
    int* bcnt     = (int*)p; p += 3200;
    int* bbase    = (int*)p; p += 3200;
    int* bcursor  = (int*)p; p += 3200;
    unsigned short* wt = (unsigned short*)p;                   // 4*128*128 bf16

    hipMemsetAsync(bcnt, 0, N_BUCKETS * sizeof(int), stream);
    k_convert_x<<<(ROWS_PAD * 128) / 256, 256, 0, stream>>>(x, xb);
    k_convert_w<<<256, 256, 0, stream>>>(w, wt);
    k_bhist<<<(N_EDGES + 8191) / 8192, 256, 0, stream>>>(ei, bcnt);
    k_bscan<<<1, 1024, 0, stream>>>(bcnt, bbase, bcursor, rowstart);
    k_bin<<<(N_EDGES + 16383) / 16384, 1024, 0, stream>>>(ei, lap, bcursor, ep_tmp);
    k_rsort<<<N_BUCKETS, 256, 0, stream>>>(ep_tmp, bbase, rowstart, ep);

    // Tx1 = L x
    k_spmm<<<ROWS_PAD / 4, 256, 0, stream>>>(xb, xb, bufA, rowstart, ep, 1.f, 0.f);
    // out = x @ W0 + Tx1 @ W1
    k_gemm2<<<ROWS_PAD / 64, 256, 0, stream>>>(xb, wt, bufA, wt + 16384, out, bias, 0);
    // Tx2 = 2 L Tx1 - x   (bufB now free: ep_tmp consumed)
    k_spmm<<<ROWS_PAD / 4, 256, 0, stream>>>(bufA, xb, bufB, rowstart, ep, 2.f, -1.f);
    // Tx3 = 2 L Tx2 - Tx1 (in place into bufA; per-thread read-before-write)
    k_spmm<<<ROWS_PAD / 4, 256, 0, stream>>>(bufB, bufA, bufA, rowstart, ep, 2.f, -1.f);
    // out += Tx2 @ W2 + Tx3 @ W3 + bias
    k_gemm2<<<ROWS_PAD / 64, 256, 0, stream>>>(bufB, wt + 2 * 16384, bufA, wt + 3 * 16384, out, bias, 1);
}

// Round 4
// 673.944 us; speedup vs baseline: 1.4833x; 1.1059x over previous
//
#include <hip/hip_runtime.h>

#define N_NODES 100000
#define N_EDGES 3200000
#define ROWS_PAD 100032   // multiple of 64 for GEMM tiling
#define N_BUCKETS 782     // ceil(100000/128)
#define BUCKET_SHIFT 7

typedef __attribute__((ext_vector_type(8))) short bf16x8;
typedef __attribute__((ext_vector_type(4))) float f32x4;
typedef __attribute__((ext_vector_type(2))) float f32x2;

__device__ __forceinline__ unsigned short f2bf(float f) {
    unsigned u = __float_as_uint(f);
    unsigned r = (u + 0x7fffu + ((u >> 16) & 1u)) >> 16;  // round-to-nearest-even
    return (unsigned short)r;
}
__device__ __forceinline__ float bflo(unsigned u) { return __uint_as_float(u << 16); }
__device__ __forceinline__ float bfhi(unsigned u) { return __uint_as_float(u & 0xffff0000u); }

// ---- convert x fp32 -> fp8 e4m3 [ROWS_PAD,128], 2 elems/thread, zero pad rows ----
__global__ void k_convert_x(const float* __restrict__ x, unsigned short* __restrict__ xf8) {
    int i = blockIdx.x * 256 + threadIdx.x;          // pair index; grid covers ROWS_PAD*64
    int r = i >> 6;
    float f0 = 0.f, f1 = 0.f;
    if (r < N_NODES) { f0 = x[2 * i]; f1 = x[2 * i + 1]; }
    int pk = __builtin_amdgcn_cvt_pk_fp8_f32(f0, f1, 0, false);
    xf8[i] = (unsigned short)(pk & 0xffff);
}

// ---- convert+transpose W [4][k][c] fp32 -> WT [4][c][k] bf16 ----
__global__ void k_convert_w(const float* __restrict__ w, unsigned short* __restrict__ wt) {
    int i = blockIdx.x * 256 + threadIdx.x;          // 65536 total
    int m = i >> 14, rem = i & 16383, k = rem >> 7, c = rem & 127;
    wt[(m << 14) + (c << 7) + k] = f2bf(w[i]);
}

// ---- coarse bucket histogram (row>>7), LDS-aggregated ----
__global__ void __launch_bounds__(256) k_bhist(const int* __restrict__ ei, int* __restrict__ bcnt) {
    __shared__ int h[N_BUCKETS];
    for (int i = threadIdx.x; i < N_BUCKETS; i += 256) h[i] = 0;
    __syncthreads();
    int base = blockIdx.x * 8192;
#pragma unroll
    for (int i = 0; i < 32; ++i) {
        int e = base + threadIdx.x + i * 256;
        if (e < N_EDGES) atomicAdd(&h[ei[e] >> BUCKET_SHIFT], 1);
    }
    __syncthreads();
    for (int i = threadIdx.x; i < N_BUCKETS; i += 256)
        if (h[i]) atomicAdd(&bcnt[i], h[i]);
}

// ---- one-block exclusive scan of bucket counts ----
__global__ void __launch_bounds__(1024) k_bscan(const int* __restrict__ bcnt,
                                                int* __restrict__ bbase,
                                                int* __restrict__ bcursor,
                                                int* __restrict__ rowstart) {
    __shared__ int s[1024];
    int t = threadIdx.x;
    int v = (t < N_BUCKETS) ? bcnt[t] : 0;
    s[t] = v;
    __syncthreads();
    for (int off = 1; off < 1024; off <<= 1) {
        int tv = (t >= off) ? s[t - off] : 0;
        __syncthreads();
        s[t] += tv;
        __syncthreads();
    }
    if (t < N_BUCKETS) {
        int ex = s[t] - v;
        bbase[t] = ex;
        bcursor[t] = ex;
    }
    if (t == 0) {
        bbase[N_BUCKETS] = N_EDGES;
        rowstart[N_NODES] = N_EDGES;
    }
}

// ---- pass 1: bin edges by coarse bucket; per-block run reservation -> L2-local scatter ----
__global__ void __launch_bounds__(1024) k_bin(const int* __restrict__ ei,
                                              const float* __restrict__ lap,
                                              int* __restrict__ bcursor,
                                              uint2* __restrict__ ep_tmp) {
    __shared__ int h[N_BUCKETS];
    __shared__ int runbase[N_BUCKETS];
    for (int i = threadIdx.x; i < N_BUCKETS; i += 1024) h[i] = 0;
    __syncthreads();
    int base = blockIdx.x * 16384;
#pragma unroll
    for (int i = 0; i < 16; ++i) {
        int e = base + threadIdx.x + i * 1024;
        if (e < N_EDGES) atomicAdd(&h[ei[e] >> BUCKET_SHIFT], 1);
    }
    __syncthreads();
    for (int i = threadIdx.x; i < N_BUCKETS; i += 1024) {
        int c = h[i];
        runbase[i] = c ? atomicAdd(&bcursor[i], c) : 0;
        h[i] = 0;   // reuse as local cursor
    }
    __syncthreads();
#pragma unroll
    for (int i = 0; i < 16; ++i) {
        int e = base + threadIdx.x + i * 1024;
        if (e < N_EDGES) {
            int row = ei[e], col = ei[N_EDGES + e];
            int b = row >> BUCKET_SHIFT;
            int p = runbase[b] + atomicAdd(&h[b], 1);
            ep_tmp[p] = make_uint2(((unsigned)(row & 127) << 17) | (unsigned)col,
                                   __float_as_uint(lap[e]));
        }
    }
}

// ---- pass 2: per-bucket row sort in LDS; emit rowstart + final ep ----
#define ST_CAP 5120
__global__ void __launch_bounds__(256) k_rsort(const uint2* __restrict__ ep_tmp,
                                               const int* __restrict__ bbase,
                                               int* __restrict__ rowstart,
                                               int2* __restrict__ ep) {
    __shared__ uint2 st[ST_CAP];
    __shared__ int h[128];
    __shared__ int lcur[128];
    int b = blockIdx.x;
    int base = bbase[b], end = bbase[b + 1];
    int n = end - base;
    if (n > ST_CAP) n = ST_CAP;   // statistically unreachable
    for (int i = threadIdx.x; i < n; i += 256) st[i] = ep_tmp[base + i];
    if (threadIdx.x < 128) h[threadIdx.x] = 0;
    __syncthreads();
    for (int i = threadIdx.x; i < n; i += 256) atomicAdd(&h[st[i].x >> 17], 1);
    __syncthreads();
    int t = threadIdx.x;
    int v = (t < 128) ? h[t] : 0;
    for (int off = 1; off < 128; off <<= 1) {
        int tv = (t < 128 && t >= off) ? h[t - off] : 0;
        __syncthreads();
        if (t < 128) h[t] += tv;
        __syncthreads();
    }
    if (t < 128) {
        int ex = h[t] - v;
        int r = (b << BUCKET_SHIFT) + t;
        if (r < N_NODES) rowstart[r] = base + ex;
        lcur[t] = base + ex;
    }
    __syncthreads();
    for (int i = threadIdx.x; i < n; i += 256) {
        uint2 s = st[i];
        int r = s.x >> 17;
        int p = atomicAdd(&lcur[r], 1);
        ep[p] = make_int2((int)(s.x & 0x1FFFFu), (int)s.y);
    }
}

// ---- SpMM gather (fp8 source), dual-format output:
//   acc = a * sum lap_e * fp8(xs[col_e]) + b * z[r]
//   yb[r] = bf16(acc) (always), y8[r] = fp8(acc) (if y8 != null)
// zmode: 0 = none, 1 = bf16 z, 3 = fp32 z. One wave per row, 2 ch/lane.
__global__ void __launch_bounds__(256) k_spmm8(
    const unsigned char* __restrict__ xs, const void* __restrict__ z, int zmode,
    unsigned short* __restrict__ y8, unsigned* __restrict__ yb,
    const int* __restrict__ rowstart, const int2* __restrict__ ep, float a, float b)
{
    int wv = threadIdx.x >> 6, lane = threadIdx.x & 63;
    int r = blockIdx.x * 4 + wv;
    if (r >= N_NODES) return;    // pad rows never stored to out (masked in GEMM)
    float acc0 = 0.f, acc1 = 0.f;
    int e0 = rowstart[r], e1 = rowstart[r + 1];
    int e = e0;
    for (; e + 8 <= e1; e += 8) {
        int2 p[8];
        unsigned short g[8];
#pragma unroll
        for (int j = 0; j < 8; ++j) p[j] = ep[e + j];
#pragma unroll
        for (int j = 0; j < 8; ++j)
            g[j] = *(const unsigned short*)(xs + (size_t)p[j].x * 128 + 2 * lane);
#pragma unroll
        for (int j = 0; j < 8; ++j) {
            float l = __int_as_float(p[j].y);
            f32x2 f = __builtin_amdgcn_cvt_pk_f32_fp8((int)g[j], false);
            acc0 += l * f.x;
            acc1 += l * f.y;
        }
    }
    for (; e < e1; ++e) {
        int2 p = ep[e];
        unsigned short g = *(const unsigned short*)(xs + (size_t)p.x * 128 + 2 * lane);
        float l = __int_as_float(p.y);
        f32x2 f = __builtin_amdgcn_cvt_pk_f32_fp8((int)g, false);
        acc0 += l * f.x;
        acc1 += l * f.y;
    }
    float o0 = a * acc0, o1 = a * acc1;
    if (zmode == 1) {
        unsigned zg = *((const unsigned*)z + (size_t)r * 64 + lane);
        o0 += b * bflo(zg);
        o1 += b * bfhi(zg);
    } else if (zmode == 3) {
        float2 zf = *((const float2*)z + (size_t)r * 64 + lane);
        o0 += b * zf.x;
        o1 += b * zf.y;
    }
    yb[(size_t)r * 64 + lane] = (unsigned)f2bf(o0) | ((unsigned)f2bf(o1) << 16);
    if (y8) {
        int pk = __builtin_amdgcn_cvt_pk_fp8_f32(o0, o1, 0, false);
        y8[(size_t)r * 64 + lane] = (unsigned short)(pk & 0xffff);
    }
}

// ---- A-fragment loader: fmt 0 = bf16, 1 = fp32 (convert, exact-ish RNE) ----
__device__ __forceinline__ void load_afrags(const void* A, int fmt, int row, int quad,
                                            bf16x8* frag) {
    if (fmt == 0) {
        const short* p = (const short*)A + (size_t)row * 128 + quad * 8;
#pragma unroll
        for (int kk = 0; kk < 4; ++kk) frag[kk] = *(const bf16x8*)(p + kk * 32);
    } else {
        const float* p = (const float*)A + (size_t)row * 128 + quad * 8;
#pragma unroll
        for (int kk = 0; kk < 4; ++kk) {
            f32x4 u = *(const f32x4*)(p + kk * 32);
            f32x4 v = *(const f32x4*)(p + kk * 32 + 4);
            bf16x8 fr;
            fr[0] = (short)f2bf(u.x); fr[1] = (short)f2bf(u.y);
            fr[2] = (short)f2bf(u.z); fr[3] = (short)f2bf(u.w);
            fr[4] = (short)f2bf(v.x); fr[5] = (short)f2bf(v.y);
            fr[6] = (short)f2bf(v.z); fr[7] = (short)f2bf(v.w);
            frag[kk] = fr;
        }
    }
}

// ---- fused MFMA GEMM pair: out (+)= A0@W0 + A1@W1 (+ bias)   mode 0: write, 1: acc+bias
__global__ void __launch_bounds__(256) k_gemm2(
    const void* __restrict__ A0, int fmt0, const unsigned short* __restrict__ WT0,
    const void* __restrict__ A1, int fmt1, const unsigned short* __restrict__ WT1,
    float* __restrict__ out, const float* __restrict__ bias, int mode)
{
    int wv = threadIdx.x >> 6, lane = threadIdx.x & 63;
    int m = lane & 15, quad = lane >> 4;
    int r0 = blockIdx.x * 64 + wv * 16;
    // fp32 sources are the raw input x [N_NODES,128]: clamp row to stay in-bounds
    // (pad rows' outputs are masked on store; row content is irrelevant there)
    int row = r0 + m;
    int row0 = (fmt0 == 1 && row >= N_NODES) ? (N_NODES - 1) : row;
    int row1 = (fmt1 == 1 && row >= N_NODES) ? (N_NODES - 1) : row;
    bf16x8 a0[4], a1[4];
    load_afrags(A0, fmt0, row0, quad, a0);
    load_afrags(A1, fmt1, row1, quad, a1);
#pragma unroll
    for (int ct = 0; ct < 8; ++ct) {
        int c0 = ct * 16;
        const short* Bp0 = (const short*)WT0 + (c0 + m) * 128 + quad * 8;
        const short* Bp1 = (const short*)WT1 + (c0 + m) * 128 + quad * 8;
        f32x4 acc0 = {0.f, 0.f, 0.f, 0.f};
        f32x4 acc1 = {0.f, 0.f, 0.f, 0.f};
#pragma unroll
        for (int kk = 0; kk < 4; ++kk) {
            bf16x8 b0 = *(const bf16x8*)(Bp0 + kk * 32);
            bf16x8 b1 = *(const bf16x8*)(Bp1 + kk * 32);
            acc0 = __builtin_amdgcn_mfma_f32_16x16x32_bf16(a0[kk], b0, acc0, 0, 0, 0);
            acc1 = __builtin_amdgcn_mfma_f32_16x16x32_bf16(a1[kk], b1, acc1, 0, 0, 0);
        }
        int c = c0 + m;                               // C/D layout: col=lane&15, row=quad*4+i
#pragma unroll
        for (int i = 0; i < 4; ++i) {
            int r = r0 + quad * 4 + i;
            if (r < N_NODES) {
                float* o = out + (size_t)r * 128 + c;
                float v = acc0[i] + acc1[i];
                if (mode == 0) *o = v;
                else           *o = *o + v + bias[c];
            }
        }
    }
}

extern "C" void kernel_launch(void* const* d_in, const int* in_sizes, int n_in,
                              void* d_out, int out_size, void* d_ws, size_t ws_size,
                              hipStream_t stream) {
    const float* x    = (const float*)d_in[0];
    const float* lap  = (const float*)d_in[1];
    const float* w    = (const float*)d_in[2];
    const float* bias = (const float*)d_in[3];
    const int*   ei   = (const int*)d_in[4];
    float* out = (float*)d_out;

    char* ws = (char*)d_ws;
    const size_t SZ_BF = (size_t)ROWS_PAD * 128 * 2;   // 25,608,192 B
    const size_t SZ_F8 = (size_t)ROWS_PAD * 128;       // 12,804,096 B
    // layout (lifetimes annotated):
    int2* ep            = (int2*)(ws);                              // [0, SZ_BF)
    unsigned char* xf8  = (unsigned char*)(ws + SZ_BF);             // dead after SpMM1
    unsigned char* t1_8 = (unsigned char*)(ws + SZ_BF + SZ_F8);     // dead after SpMM2
    unsigned char* t3_b = (unsigned char*)(ws + SZ_BF);             // reuses xf8+t1_8 region (bf16)
    unsigned char* t1_b = (unsigned char*)(ws + 2 * SZ_BF);
    unsigned char* t2_8 = (unsigned char*)(ws + 3 * SZ_BF);
    unsigned char* t2_b = (unsigned char*)(ws + 3 * SZ_BF + SZ_F8);
    uint2* ep_tmp       = (uint2*)(ws + 3 * SZ_BF);                 // aliases t2_8 + t2_b head; dead after rsort
    char* p = ws + 4 * SZ_BF + SZ_F8;
    int* rowstart = (int*)p; p += 400128;
    int* bcnt     = (int*)p; p += 3200;
    int* bbase    = (int*)p; p += 3200;
    int* bcursor  = (int*)p; p += 3200;
    unsigned short* wt = (unsigned short*)p;           // 4*128*128 bf16

    hipMemsetAsync(bcnt, 0, N_BUCKETS * sizeof(int), stream);
    k_convert_x<<<(ROWS_PAD * 64) / 256, 256, 0, stream>>>(x, (unsigned short*)xf8);
    k_convert_w<<<256, 256, 0, stream>>>(w, wt);
    k_bhist<<<(N_EDGES + 8191) / 8192, 256, 0, stream>>>(ei, bcnt);
    k_bscan<<<1, 1024, 0, stream>>>(bcnt, bbase, bcursor, rowstart);
    k_bin<<<(N_EDGES + 16383) / 16384, 1024, 0, stream>>>(ei, lap, bcursor, ep_tmp);
    k_rsort<<<N_BUCKETS, 256, 0, stream>>>(ep_tmp, bbase, rowstart, ep);

    // Tx1 = L x          (gather fp8 x; write bf16 + fp8)
    k_spmm8<<<ROWS_PAD / 4, 256, 0, stream>>>(xf8, nullptr, 0,
        (unsigned short*)t1_8, (unsigned*)t1_b, rowstart, ep, 1.f, 0.f);
    // out = x @ W0 + Tx1 @ W1    (x fp32 direct, Tx1 bf16)
    k_gemm2<<<ROWS_PAD / 64, 256, 0, stream>>>(x, 1, wt, t1_b, 0, wt + 16384, out, bias, 0);
    // Tx2 = 2 L Tx1 - x  (gather fp8 Tx1; z fp32 x; write bf16 + fp8)
    k_spmm8<<<ROWS_PAD / 4, 256, 0, stream>>>(t1_8, x, 3,
        (unsigned short*)t2_8, (unsigned*)t2_b, rowstart, ep, 2.f, -1.f);
    // Tx3 = 2 L Tx2 - Tx1 (gather fp8 Tx2; z bf16 Tx1; write bf16 only, into dead xf8/t1_8 region)
    k_spmm8<<<ROWS_PAD / 4, 256, 0, stream>>>(t2_8, t1_b, 1,
        nullptr, (unsigned*)t3_b, rowstart, ep, 2.f, -1.f);
    // out += Tx2 @ W2 + Tx3 @ W3 + bias
    k_gemm2<<<ROWS_PAD / 64, 256, 0, stream>>>(t2_b, 0, wt + 2 * 16384, t3_b, 0, wt + 3 * 16384, out, bias, 1);
}

// Round 5
// 650.779 us; speedup vs baseline: 1.5361x; 1.0356x over previous
//
#include <hip/hip_runtime.h>

#define N_NODES 100000
#define N_EDGES 3200000
#define ROWS_PAD 100032   // multiple of 64 for GEMM tiling
#define N_BUCKETS 782     // ceil(100000/128)
#define BUCKET_SHIFT 7

typedef __attribute__((ext_vector_type(8))) short bf16x8;
typedef __attribute__((ext_vector_type(4))) float f32x4;
typedef __attribute__((ext_vector_type(2))) float f32x2;

__device__ __forceinline__ unsigned short f2bf(float f) {
    unsigned u = __float_as_uint(f);
    unsigned r = (u + 0x7fffu + ((u >> 16) & 1u)) >> 16;  // round-to-nearest-even
    return (unsigned short)r;
}
__device__ __forceinline__ float bflo(unsigned u) { return __uint_as_float(u << 16); }
__device__ __forceinline__ float bfhi(unsigned u) { return __uint_as_float(u & 0xffff0000u); }

// ---- convert x fp32 -> fp8 e4m3 [ROWS_PAD,128], 2 elems/thread, zero pad rows ----
__global__ void k_convert_x(const float* __restrict__ x, unsigned short* __restrict__ xf8) {
    int i = blockIdx.x * 256 + threadIdx.x;          // pair index; grid covers ROWS_PAD*64
    int r = i >> 6;
    float f0 = 0.f, f1 = 0.f;
    if (r < N_NODES) { f0 = x[2 * i]; f1 = x[2 * i + 1]; }
    int pk = __builtin_amdgcn_cvt_pk_fp8_f32(f0, f1, 0, false);
    xf8[i] = (unsigned short)(pk & 0xffff);
}

// ---- convert+transpose W [4][k][c] fp32 -> WT [4][c][k] bf16 ----
__global__ void k_convert_w(const float* __restrict__ w, unsigned short* __restrict__ wt) {
    int i = blockIdx.x * 256 + threadIdx.x;          // 65536 total
    int m = i >> 14, rem = i & 16383, k = rem >> 7, c = rem & 127;
    wt[(m << 14) + (c << 7) + k] = f2bf(w[i]);
}

// ---- coarse bucket histogram (row>>7), LDS-aggregated ----
__global__ void __launch_bounds__(256) k_bhist(const int* __restrict__ ei, int* __restrict__ bcnt) {
    __shared__ int h[N_BUCKETS];
    for (int i = threadIdx.x; i < N_BUCKETS; i += 256) h[i] = 0;
    __syncthreads();
    int base = blockIdx.x * 8192;
#pragma unroll
    for (int i = 0; i < 32; ++i) {
        int e = base + threadIdx.x + i * 256;
        if (e < N_EDGES) atomicAdd(&h[ei[e] >> BUCKET_SHIFT], 1);
    }
    __syncthreads();
    for (int i = threadIdx.x; i < N_BUCKETS; i += 256)
        if (h[i]) atomicAdd(&bcnt[i], h[i]);
}

// ---- one-block exclusive scan of bucket counts ----
__global__ void __launch_bounds__(1024) k_bscan(const int* __restrict__ bcnt,
                                                int* __restrict__ bbase,
                                                int* __restrict__ bcursor,
                                                int* __restrict__ rowstart) {
    __shared__ int s[1024];
    int t = threadIdx.x;
    int v = (t < N_BUCKETS) ? bcnt[t] : 0;
    s[t] = v;
    __syncthreads();
    for (int off = 1; off < 1024; off <<= 1) {
        int tv = (t >= off) ? s[t - off] : 0;
        __syncthreads();
        s[t] += tv;
        __syncthreads();
    }
    if (t < N_BUCKETS) {
        int ex = s[t] - v;
        bbase[t] = ex;
        bcursor[t] = ex;
    }
    if (t == 0) {
        bbase[N_BUCKETS] = N_EDGES;
        rowstart[N_NODES] = N_EDGES;
    }
}

// ---- pass 1: bin edges by coarse bucket; per-block run reservation -> L2-local scatter ----
__global__ void __launch_bounds__(1024) k_bin(const int* __restrict__ ei,
                                              const float* __restrict__ lap,
                                              int* __restrict__ bcursor,
                                              uint2* __restrict__ ep_tmp) {
    __shared__ int h[N_BUCKETS];
    __shared__ int runbase[N_BUCKETS];
    for (int i = threadIdx.x; i < N_BUCKETS; i += 1024) h[i] = 0;
    __syncthreads();
    int base = blockIdx.x * 16384;
#pragma unroll
    for (int i = 0; i < 16; ++i) {
        int e = base + threadIdx.x + i * 1024;
        if (e < N_EDGES) atomicAdd(&h[ei[e] >> BUCKET_SHIFT], 1);
    }
    __syncthreads();
    for (int i = threadIdx.x; i < N_BUCKETS; i += 1024) {
        int c = h[i];
        runbase[i] = c ? atomicAdd(&bcursor[i], c) : 0;
        h[i] = 0;   // reuse as local cursor
    }
    __syncthreads();
#pragma unroll
    for (int i = 0; i < 16; ++i) {
        int e = base + threadIdx.x + i * 1024;
        if (e < N_EDGES) {
            int row = ei[e], col = ei[N_EDGES + e];
            int b = row >> BUCKET_SHIFT;
            int p = runbase[b] + atomicAdd(&h[b], 1);
            ep_tmp[p] = make_uint2(((unsigned)(row & 127) << 17) | (unsigned)col,
                                   __float_as_uint(lap[e]));
        }
    }
}

// ---- pass 2: per-bucket row sort in LDS; emit rowstart + final ep ----
#define ST_CAP 5120
__global__ void __launch_bounds__(256) k_rsort(const uint2* __restrict__ ep_tmp,
                                               const int* __restrict__ bbase,
                                               int* __restrict__ rowstart,
                                               int2* __restrict__ ep) {
    __shared__ uint2 st[ST_CAP];
    __shared__ int h[128];
    __shared__ int lcur[128];
    int b = blockIdx.x;
    int base = bbase[b], end = bbase[b + 1];
    int n = end - base;
    if (n > ST_CAP) n = ST_CAP;   // statistically unreachable
    for (int i = threadIdx.x; i < n; i += 256) st[i] = ep_tmp[base + i];
    if (threadIdx.x < 128) h[threadIdx.x] = 0;
    __syncthreads();
    for (int i = threadIdx.x; i < n; i += 256) atomicAdd(&h[st[i].x >> 17], 1);
    __syncthreads();
    int t = threadIdx.x;
    int v = (t < 128) ? h[t] : 0;
    for (int off = 1; off < 128; off <<= 1) {
        int tv = (t < 128 && t >= off) ? h[t - off] : 0;
        __syncthreads();
        if (t < 128) h[t] += tv;
        __syncthreads();
    }
    if (t < 128) {
        int ex = h[t] - v;
        int r = (b << BUCKET_SHIFT) + t;
        if (r < N_NODES) rowstart[r] = base + ex;
        lcur[t] = base + ex;
    }
    __syncthreads();
    for (int i = threadIdx.x; i < n; i += 256) {
        uint2 s = st[i];
        int r = s.x >> 17;
        int p = atomicAdd(&lcur[r], 1);
        ep[p] = make_int2((int)(s.x & 0x1FFFFu), (int)s.y);
    }
}

// ---- SpMM gather (fp8 source), pair-edge scheme:
// lanes 0-31 process even-slot edges, 32-63 odd-slot; each lane loads 4 B = 4 channels.
// Butterfly-merge halves, then lanes 0-31 add z and store bf16 (+fp8).
// zmode: 0 = none, 1 = bf16 z, 3 = fp32 z.
__global__ void __launch_bounds__(256) k_spmm8(
    const unsigned char* __restrict__ xs, const void* __restrict__ z, int zmode,
    unsigned* __restrict__ y8, uint2* __restrict__ yb,
    const int* __restrict__ rowstart, const int2* __restrict__ ep, float a, float b)
{
    int wv = threadIdx.x >> 6, lane = threadIdx.x & 63;
    int r = blockIdx.x * 4 + wv;
    if (r >= N_NODES) return;    // pad rows never stored to out (masked in GEMM)
    int half = lane >> 5, c = lane & 31;
    float acc0 = 0.f, acc1 = 0.f, acc2 = 0.f, acc3 = 0.f;   // channels 4c..4c+3
    int e0 = rowstart[r], e1 = rowstart[r + 1];
    int e = e0;
    for (; e + 16 <= e1; e += 16) {          // 16 edges per iter: 8 pairs
        int2 p[8];
        unsigned g[8];
#pragma unroll
        for (int j = 0; j < 8; ++j) p[j] = ep[e + 2 * j + half];
#pragma unroll
        for (int j = 0; j < 8; ++j)
            g[j] = *(const unsigned*)(xs + (size_t)p[j].x * 128 + c * 4);
#pragma unroll
        for (int j = 0; j < 8; ++j) {
            float l = __int_as_float(p[j].y);
            f32x2 flo = __builtin_amdgcn_cvt_pk_f32_fp8((int)g[j], false);
            f32x2 fhi = __builtin_amdgcn_cvt_pk_f32_fp8((int)g[j], true);
            acc0 += l * flo.x; acc1 += l * flo.y;
            acc2 += l * fhi.x; acc3 += l * fhi.y;
        }
    }
    for (; e + 2 <= e1; e += 2) {            // pair tail
        int2 p = ep[e + half];
        unsigned g = *(const unsigned*)(xs + (size_t)p.x * 128 + c * 4);
        float l = __int_as_float(p.y);
        f32x2 flo = __builtin_amdgcn_cvt_pk_f32_fp8((int)g, false);
        f32x2 fhi = __builtin_amdgcn_cvt_pk_f32_fp8((int)g, true);
        acc0 += l * flo.x; acc1 += l * flo.y;
        acc2 += l * fhi.x; acc3 += l * fhi.y;
    }
    if (e < e1 && half == 0) {               // odd last edge: half 0 only
        int2 p = ep[e];
        unsigned g = *(const unsigned*)(xs + (size_t)p.x * 128 + c * 4);
        float l = __int_as_float(p.y);
        f32x2 flo = __builtin_amdgcn_cvt_pk_f32_fp8((int)g, false);
        f32x2 fhi = __builtin_amdgcn_cvt_pk_f32_fp8((int)g, true);
        acc0 += l * flo.x; acc1 += l * flo.y;
        acc2 += l * fhi.x; acc3 += l * fhi.y;
    }
    // butterfly-merge the two halves (lane c <-> lane c+32)
    acc0 += __shfl(acc0, lane ^ 32, 64);
    acc1 += __shfl(acc1, lane ^ 32, 64);
    acc2 += __shfl(acc2, lane ^ 32, 64);
    acc3 += __shfl(acc3, lane ^ 32, 64);
    if (half == 0) {
        float o0 = a * acc0, o1 = a * acc1, o2 = a * acc2, o3 = a * acc3;
        if (zmode == 1) {
            uint2 zg = *((const uint2*)z + (size_t)r * 32 + c);
            o0 += b * bflo(zg.x); o1 += b * bfhi(zg.x);
            o2 += b * bflo(zg.y); o3 += b * bfhi(zg.y);
        } else if (zmode == 3) {
            f32x4 zf = *((const f32x4*)z + (size_t)r * 32 + c);
            o0 += b * zf.x; o1 += b * zf.y; o2 += b * zf.z; o3 += b * zf.w;
        }
        uint2 ob;
        ob.x = (unsigned)f2bf(o0) | ((unsigned)f2bf(o1) << 16);
        ob.y = (unsigned)f2bf(o2) | ((unsigned)f2bf(o3) << 16);
        yb[(size_t)r * 32 + c] = ob;
        if (y8) {
            int pk = __builtin_amdgcn_cvt_pk_fp8_f32(o0, o1, 0, false);
            pk = __builtin_amdgcn_cvt_pk_fp8_f32(o2, o3, pk, true);
            y8[(size_t)r * 32 + c] = (unsigned)pk;
        }
    }
}

// ---- A-fragment loader: fmt 0 = bf16, 1 = fp32 (convert, RNE) ----
__device__ __forceinline__ void load_afrags(const void* A, int fmt, int row, int quad,
                                            bf16x8* frag) {
    if (fmt == 0) {
        const short* p = (const short*)A + (size_t)row * 128 + quad * 8;
#pragma unroll
        for (int kk = 0; kk < 4; ++kk) frag[kk] = *(const bf16x8*)(p + kk * 32);
    } else {
        const float* p = (const float*)A + (size_t)row * 128 + quad * 8;
#pragma unroll
        for (int kk = 0; kk < 4; ++kk) {
            f32x4 u = *(const f32x4*)(p + kk * 32);
            f32x4 v = *(const f32x4*)(p + kk * 32 + 4);
            bf16x8 fr;
            fr[0] = (short)f2bf(u.x); fr[1] = (short)f2bf(u.y);
            fr[2] = (short)f2bf(u.z); fr[3] = (short)f2bf(u.w);
            fr[4] = (short)f2bf(v.x); fr[5] = (short)f2bf(v.y);
            fr[6] = (short)f2bf(v.z); fr[7] = (short)f2bf(v.w);
            frag[kk] = fr;
        }
    }
}

// ---- fused MFMA GEMM pair: out (+)= A0@W0 + A1@W1 (+ bias)   mode 0: write, 1: acc+bias
__global__ void __launch_bounds__(256) k_gemm2(
    const void* __restrict__ A0, int fmt0, const unsigned short* __restrict__ WT0,
    const void* __restrict__ A1, int fmt1, const unsigned short* __restrict__ WT1,
    float* __restrict__ out, const float* __restrict__ bias, int mode)
{
    int wv = threadIdx.x >> 6, lane = threadIdx.x & 63;
    int m = lane & 15, quad = lane >> 4;
    int r0 = blockIdx.x * 64 + wv * 16;
    // fp32 sources are the raw input x [N_NODES,128]: clamp row to stay in-bounds
    int row = r0 + m;
    int row0 = (fmt0 == 1 && row >= N_NODES) ? (N_NODES - 1) : row;
    int row1 = (fmt1 == 1 && row >= N_NODES) ? (N_NODES - 1) : row;
    bf16x8 a0[4], a1[4];
    load_afrags(A0, fmt0, row0, quad, a0);
    load_afrags(A1, fmt1, row1, quad, a1);
#pragma unroll
    for (int ct = 0; ct < 8; ++ct) {
        int c0 = ct * 16;
        const short* Bp0 = (const short*)WT0 + (c0 + m) * 128 + quad * 8;
        const short* Bp1 = (const short*)WT1 + (c0 + m) * 128 + quad * 8;
        f32x4 acc0 = {0.f, 0.f, 0.f, 0.f};
        f32x4 acc1 = {0.f, 0.f, 0.f, 0.f};
#pragma unroll
        for (int kk = 0; kk < 4; ++kk) {
            bf16x8 b0 = *(const bf16x8*)(Bp0 + kk * 32);
            bf16x8 b1 = *(const bf16x8*)(Bp1 + kk * 32);
            acc0 = __builtin_amdgcn_mfma_f32_16x16x32_bf16(a0[kk], b0, acc0, 0, 0, 0);
            acc1 = __builtin_amdgcn_mfma_f32_16x16x32_bf16(a1[kk], b1, acc1, 0, 0, 0);
        }
        int c = c0 + m;                               // C/D layout: col=lane&15, row=quad*4+i
#pragma unroll
        for (int i = 0; i < 4; ++i) {
            int r = r0 + quad * 4 + i;
            if (r < N_NODES) {
                float* o = out + (size_t)r * 128 + c;
                float v = acc0[i] + acc1[i];
                if (mode == 0) *o = v;
                else           *o = *o + v + bias[c];
            }
        }
    }
}

extern "C" void kernel_launch(void* const* d_in, const int* in_sizes, int n_in,
                              void* d_out, int out_size, void* d_ws, size_t ws_size,
                              hipStream_t stream) {
    const float* x    = (const float*)d_in[0];
    const float* lap  = (const float*)d_in[1];
    const float* w    = (const float*)d_in[2];
    const float* bias = (const float*)d_in[3];
    const int*   ei   = (const int*)d_in[4];
    float* out = (float*)d_out;

    char* ws = (char*)d_ws;
    const size_t SZ_BF = (size_t)ROWS_PAD * 128 * 2;   // 25,608,192 B
    const size_t SZ_F8 = (size_t)ROWS_PAD * 128;       // 12,804,096 B
    // layout (lifetimes annotated):
    int2* ep            = (int2*)(ws);                              // [0, SZ_BF)
    unsigned char* xf8  = (unsigned char*)(ws + SZ_BF);             // dead after SpMM1
    unsigned char* t1_8 = (unsigned char*)(ws + SZ_BF + SZ_F8);     // dead after SpMM2
    unsigned char* t3_b = (unsigned char*)(ws + SZ_BF);             // reuses xf8+t1_8 region (bf16)
    unsigned char* t1_b = (unsigned char*)(ws + 2 * SZ_BF);
    unsigned char* t2_8 = (unsigned char*)(ws + 3 * SZ_BF);
    unsigned char* t2_b = (unsigned char*)(ws + 3 * SZ_BF + SZ_F8);
    uint2* ep_tmp       = (uint2*)(ws + 3 * SZ_BF);                 // aliases t2_8 + t2_b head; dead after rsort
    char* p = ws + 4 * SZ_BF + SZ_F8;
    int* rowstart = (int*)p; p += 400128;
    int* bcnt     = (int*)p; p += 3200;
    int* bbase    = (int*)p; p += 3200;
    int* bcursor  = (int*)p; p += 3200;
    unsigned short* wt = (unsigned short*)p;           // 4*128*128 bf16

    hipMemsetAsync(bcnt, 0, N_BUCKETS * sizeof(int), stream);
    k_convert_x<<<(ROWS_PAD * 64) / 256, 256, 0, stream>>>(x, (unsigned short*)xf8);
    k_convert_w<<<256, 256, 0, stream>>>(w, wt);
    k_bhist<<<(N_EDGES + 8191) / 8192, 256, 0, stream>>>(ei, bcnt);
    k_bscan<<<1, 1024, 0, stream>>>(bcnt, bbase, bcursor, rowstart);
    k_bin<<<(N_EDGES + 16383) / 16384, 1024, 0, stream>>>(ei, lap, bcursor, ep_tmp);
    k_rsort<<<N_BUCKETS, 256, 0, stream>>>(ep_tmp, bbase, rowstart, ep);

    // Tx1 = L x          (gather fp8 x; write bf16 + fp8)
    k_spmm8<<<ROWS_PAD / 4, 256, 0, stream>>>(xf8, nullptr, 0,
        (unsigned*)t1_8, (uint2*)t1_b, rowstart, ep, 1.f, 0.f);
    // out = x @ W0 + Tx1 @ W1    (x fp32 direct, Tx1 bf16)
    k_gemm2<<<ROWS_PAD / 64, 256, 0, stream>>>(x, 1, wt, t1_b, 0, wt + 16384, out, bias, 0);
    // Tx2 = 2 L Tx1 - x  (gather fp8 Tx1; z fp32 x; write bf16 + fp8)
    k_spmm8<<<ROWS_PAD / 4, 256, 0, stream>>>(t1_8, x, 3,
        (unsigned*)t2_8, (uint2*)t2_b, rowstart, ep, 2.f, -1.f);
    // Tx3 = 2 L Tx2 - Tx1 (gather fp8 Tx2; z bf16 Tx1; write bf16 only, into dead xf8/t1_8 region)
    k_spmm8<<<ROWS_PAD / 4, 256, 0, stream>>>(t2_8, t1_b, 1,
        nullptr, (uint2*)t3_b, rowstart, ep, 2.f, -1.f);
    // out += Tx2 @ W2 + Tx3 @ W3 + bias
    k_gemm2<<<ROWS_PAD / 64, 256, 0, stream>>>(t2_b, 0, wt + 2 * 16384, t3_b, 0, wt + 3 * 16384, out, bias, 1);
}

// Round 6
// 625.043 us; speedup vs baseline: 1.5994x; 1.0412x over previous
//
#include <hip/hip_runtime.h>

#define N_NODES 100000
#define N_EDGES 3200000
#define ROWS_PAD 100032   // multiple of 64 for GEMM tiling
#define N_BUCKETS 782     // ceil(100000/128)
#define BUCKET_SHIFT 7

typedef __attribute__((ext_vector_type(8))) short bf16x8;
typedef __attribute__((ext_vector_type(4))) float f32x4;
typedef __attribute__((ext_vector_type(2))) float f32x2;

__device__ __forceinline__ unsigned short f2bf(float f) {
    unsigned u = __float_as_uint(f);
    unsigned r = (u + 0x7fffu + ((u >> 16) & 1u)) >> 16;  // round-to-nearest-even
    return (unsigned short)r;
}
__device__ __forceinline__ float bflo(unsigned u) { return __uint_as_float(u << 16); }
__device__ __forceinline__ float bfhi(unsigned u) { return __uint_as_float(u & 0xffff0000u); }

// ---- convert x fp32 -> fp8 e4m3 [ROWS_PAD,128], 2 elems/thread, zero pad rows ----
__global__ void k_convert_x(const float* __restrict__ x, unsigned short* __restrict__ xf8) {
    int i = blockIdx.x * 256 + threadIdx.x;          // pair index; grid covers ROWS_PAD*64
    int r = i >> 6;
    float f0 = 0.f, f1 = 0.f;
    if (r < N_NODES) { f0 = x[2 * i]; f1 = x[2 * i + 1]; }
    int pk = __builtin_amdgcn_cvt_pk_fp8_f32(f0, f1, 0, false);
    xf8[i] = (unsigned short)(pk & 0xffff);
}

// ---- convert+transpose W [4][k][c] fp32 -> WT [4][c][k] bf16 ----
__global__ void k_convert_w(const float* __restrict__ w, unsigned short* __restrict__ wt) {
    int i = blockIdx.x * 256 + threadIdx.x;          // 65536 total
    int m = i >> 14, rem = i & 16383, k = rem >> 7, c = rem & 127;
    wt[(m << 14) + (c << 7) + k] = f2bf(w[i]);
}

// ---- coarse bucket histogram (row>>7), LDS-aggregated ----
__global__ void __launch_bounds__(256) k_bhist(const int* __restrict__ ei, int* __restrict__ bcnt) {
    __shared__ int h[N_BUCKETS];
    for (int i = threadIdx.x; i < N_BUCKETS; i += 256) h[i] = 0;
    __syncthreads();
    int base = blockIdx.x * 8192;
#pragma unroll
    for (int i = 0; i < 32; ++i) {
        int e = base + threadIdx.x + i * 256;
        if (e < N_EDGES) atomicAdd(&h[ei[e] >> BUCKET_SHIFT], 1);
    }
    __syncthreads();
    for (int i = threadIdx.x; i < N_BUCKETS; i += 256)
        if (h[i]) atomicAdd(&bcnt[i], h[i]);
}

// ---- one-block exclusive scan of bucket counts ----
__global__ void __launch_bounds__(1024) k_bscan(const int* __restrict__ bcnt,
                                                int* __restrict__ bbase,
                                                int* __restrict__ bcursor,
                                                int* __restrict__ rowstart) {
    __shared__ int s[1024];
    int t = threadIdx.x;
    int v = (t < N_BUCKETS) ? bcnt[t] : 0;
    s[t] = v;
    __syncthreads();
    for (int off = 1; off < 1024; off <<= 1) {
        int tv = (t >= off) ? s[t - off] : 0;
        __syncthreads();
        s[t] += tv;
        __syncthreads();
    }
    if (t < N_BUCKETS) {
        int ex = s[t] - v;
        bbase[t] = ex;
        bcursor[t] = ex;
    }
    if (t == 0) {
        bbase[N_BUCKETS] = N_EDGES;
        rowstart[N_NODES] = N_EDGES;
    }
}

// ---- pass 1: bin edges by coarse bucket; per-block run reservation -> L2-local scatter ----
__global__ void __launch_bounds__(1024) k_bin(const int* __restrict__ ei,
                                              const float* __restrict__ lap,
                                              int* __restrict__ bcursor,
                                              uint2* __restrict__ ep_tmp) {
    __shared__ int h[N_BUCKETS];
    __shared__ int runbase[N_BUCKETS];
    for (int i = threadIdx.x; i < N_BUCKETS; i += 1024) h[i] = 0;
    __syncthreads();
    int base = blockIdx.x * 16384;
#pragma unroll
    for (int i = 0; i < 16; ++i) {
        int e = base + threadIdx.x + i * 1024;
        if (e < N_EDGES) atomicAdd(&h[ei[e] >> BUCKET_SHIFT], 1);
    }
    __syncthreads();
    for (int i = threadIdx.x; i < N_BUCKETS; i += 1024) {
        int c = h[i];
        runbase[i] = c ? atomicAdd(&bcursor[i], c) : 0;
        h[i] = 0;   // reuse as local cursor
    }
    __syncthreads();
#pragma unroll
    for (int i = 0; i < 16; ++i) {
        int e = base + threadIdx.x + i * 1024;
        if (e < N_EDGES) {
            int row = ei[e], col = ei[N_EDGES + e];
            int b = row >> BUCKET_SHIFT;
            int p = runbase[b] + atomicAdd(&h[b], 1);
            ep_tmp[p] = make_uint2(((unsigned)(row & 127) << 17) | (unsigned)col,
                                   __float_as_uint(lap[e]));
        }
    }
}

// ---- pass 2: per-bucket row sort in LDS; emit rowstart + final ep ----
#define ST_CAP 5120
__global__ void __launch_bounds__(256) k_rsort(const uint2* __restrict__ ep_tmp,
                                               const int* __restrict__ bbase,
                                               int* __restrict__ rowstart,
                                               int2* __restrict__ ep) {
    __shared__ uint2 st[ST_CAP];
    __shared__ int h[128];
    __shared__ int lcur[128];
    int b = blockIdx.x;
    int base = bbase[b], end = bbase[b + 1];
    int n = end - base;
    if (n > ST_CAP) n = ST_CAP;   // statistically unreachable
    for (int i = threadIdx.x; i < n; i += 256) st[i] = ep_tmp[base + i];
    if (threadIdx.x < 128) h[threadIdx.x] = 0;
    __syncthreads();
    for (int i = threadIdx.x; i < n; i += 256) atomicAdd(&h[st[i].x >> 17], 1);
    __syncthreads();
    int t = threadIdx.x;
    int v = (t < 128) ? h[t] : 0;
    for (int off = 1; off < 128; off <<= 1) {
        int tv = (t < 128 && t >= off) ? h[t - off] : 0;
        __syncthreads();
        if (t < 128) h[t] += tv;
        __syncthreads();
    }
    if (t < 128) {
        int ex = h[t] - v;
        int r = (b << BUCKET_SHIFT) + t;
        if (r < N_NODES) rowstart[r] = base + ex;
        lcur[t] = base + ex;
    }
    __syncthreads();
    for (int i = threadIdx.x; i < n; i += 256) {
        uint2 s = st[i];
        int r = s.x >> 17;
        int p = atomicAdd(&lcur[r], 1);
        ep[p] = make_int2((int)(s.x & 0x1FFFFu), (int)s.y);
    }
}

// ---- SpMM gather (fp8 source), pair-edge + software pipeline + masked batches:
// lanes 0-31 process even-slot edges, 32-63 odd-slot; each lane loads 4 B = 4 channels.
// All batches are 8 pairs (16 edges); out-of-range slots clamp the index and zero lap.
// ep loads for batch i+1 issue while batch i's gathers are in flight.
// zmode: 0 = none, 1 = bf16 z, 3 = fp32 z.
__global__ void __launch_bounds__(256) k_spmm8(
    const unsigned char* __restrict__ xs, const void* __restrict__ z, int zmode,
    unsigned* __restrict__ y8, uint2* __restrict__ yb,
    const int* __restrict__ rowstart, const int2* __restrict__ ep, float a, float b)
{
    int wv = threadIdx.x >> 6, lane = threadIdx.x & 63;
    int r = blockIdx.x * 4 + wv;
    if (r >= N_NODES) return;    // pad rows never stored to out (masked in GEMM)
    int half = lane >> 5, c = lane & 31;
    float acc0 = 0.f, acc1 = 0.f, acc2 = 0.f, acc3 = 0.f;   // channels 4c..4c+3
    int e0 = rowstart[r], e1 = rowstart[r + 1];
    int cnt = e1 - e0;
    if (cnt > 0) {
        int niter = (cnt + 15) >> 4;      // 16 edges per batch
        int2 pA[8], pB[8];
        // prologue: masked-load batch 0
#pragma unroll
        for (int j = 0; j < 8; ++j) {
            int idx = e0 + 2 * j + half;
            int cl = idx < e1 ? idx : e1 - 1;
            int2 p = ep[cl];
            p.y = idx < e1 ? p.y : 0;     // zero lap for masked slots
            pA[j] = p;
        }
        for (int it = 0; it < niter; ++it) {
            // 1) issue gathers for current batch
            unsigned g[8];
#pragma unroll
            for (int j = 0; j < 8; ++j)
                g[j] = *(const unsigned*)(xs + (size_t)pA[j].x * 128 + c * 4);
            // 2) issue ep loads for next batch (overlap with gathers in flight)
            if (it + 1 < niter) {
                int ebase = e0 + (it + 1) * 16;
#pragma unroll
                for (int j = 0; j < 8; ++j) {
                    int idx = ebase + 2 * j + half;
                    int cl = idx < e1 ? idx : e1 - 1;
                    int2 p = ep[cl];
                    p.y = idx < e1 ? p.y : 0;
                    pB[j] = p;
                }
            }
            // 3) consume gathers
#pragma unroll
            for (int j = 0; j < 8; ++j) {
                float l = __int_as_float(pA[j].y);
                f32x2 flo = __builtin_amdgcn_cvt_pk_f32_fp8((int)g[j], false);
                f32x2 fhi = __builtin_amdgcn_cvt_pk_f32_fp8((int)g[j], true);
                acc0 += l * flo.x; acc1 += l * flo.y;
                acc2 += l * fhi.x; acc3 += l * fhi.y;
            }
            // 4) rotate
#pragma unroll
            for (int j = 0; j < 8; ++j) pA[j] = pB[j];
        }
    }
    // butterfly-merge the two halves (lane c <-> lane c+32)
    acc0 += __shfl(acc0, lane ^ 32, 64);
    acc1 += __shfl(acc1, lane ^ 32, 64);
    acc2 += __shfl(acc2, lane ^ 32, 64);
    acc3 += __shfl(acc3, lane ^ 32, 64);
    if (half == 0) {
        float o0 = a * acc0, o1 = a * acc1, o2 = a * acc2, o3 = a * acc3;
        if (zmode == 1) {
            uint2 zg = *((const uint2*)z + (size_t)r * 32 + c);
            o0 += b * bflo(zg.x); o1 += b * bfhi(zg.x);
            o2 += b * bflo(zg.y); o3 += b * bfhi(zg.y);
        } else if (zmode == 3) {
            f32x4 zf = *((const f32x4*)z + (size_t)r * 32 + c);
            o0 += b * zf.x; o1 += b * zf.y; o2 += b * zf.z; o3 += b * zf.w;
        }
        uint2 ob;
        ob.x = (unsigned)f2bf(o0) | ((unsigned)f2bf(o1) << 16);
        ob.y = (unsigned)f2bf(o2) | ((unsigned)f2bf(o3) << 16);
        yb[(size_t)r * 32 + c] = ob;
        if (y8) {
            int pk = __builtin_amdgcn_cvt_pk_fp8_f32(o0, o1, 0, false);
            pk = __builtin_amdgcn_cvt_pk_fp8_f32(o2, o3, pk, true);
            y8[(size_t)r * 32 + c] = (unsigned)pk;
        }
    }
}

// ---- A-fragment loader: fmt 0 = bf16, 1 = fp32 (convert, RNE) ----
__device__ __forceinline__ void load_afrags(const void* A, int fmt, int row, int quad,
                                            bf16x8* frag) {
    if (fmt == 0) {
        const short* p = (const short*)A + (size_t)row * 128 + quad * 8;
#pragma unroll
        for (int kk = 0; kk < 4; ++kk) frag[kk] = *(const bf16x8*)(p + kk * 32);
    } else {
        const float* p = (const float*)A + (size_t)row * 128 + quad * 8;
#pragma unroll
        for (int kk = 0; kk < 4; ++kk) {
            f32x4 u = *(const f32x4*)(p + kk * 32);
            f32x4 v = *(const f32x4*)(p + kk * 32 + 4);
            bf16x8 fr;
            fr[0] = (short)f2bf(u.x); fr[1] = (short)f2bf(u.y);
            fr[2] = (short)f2bf(u.z); fr[3] = (short)f2bf(u.w);
            fr[4] = (short)f2bf(v.x); fr[5] = (short)f2bf(v.y);
            fr[6] = (short)f2bf(v.z); fr[7] = (short)f2bf(v.w);
            frag[kk] = fr;
        }
    }
}

// ---- fused MFMA GEMM pair: out (+)= A0@W0 + A1@W1 (+ bias)   mode 0: write, 1: acc+bias
__global__ void __launch_bounds__(256) k_gemm2(
    const void* __restrict__ A0, int fmt0, const unsigned short* __restrict__ WT0,
    const void* __restrict__ A1, int fmt1, const unsigned short* __restrict__ WT1,
    float* __restrict__ out, const float* __restrict__ bias, int mode)
{
    int wv = threadIdx.x >> 6, lane = threadIdx.x & 63;
    int m = lane & 15, quad = lane >> 4;
    int r0 = blockIdx.x * 64 + wv * 16;
    // fp32 sources are the raw input x [N_NODES,128]: clamp row to stay in-bounds
    int row = r0 + m;
    int row0 = (fmt0 == 1 && row >= N_NODES) ? (N_NODES - 1) : row;
    int row1 = (fmt1 == 1 && row >= N_NODES) ? (N_NODES - 1) : row;
    bf16x8 a0[4], a1[4];
    load_afrags(A0, fmt0, row0, quad, a0);
    load_afrags(A1, fmt1, row1, quad, a1);
#pragma unroll
    for (int ct = 0; ct < 8; ++ct) {
        int c0 = ct * 16;
        const short* Bp0 = (const short*)WT0 + (c0 + m) * 128 + quad * 8;
        const short* Bp1 = (const short*)WT1 + (c0 + m) * 128 + quad * 8;
        f32x4 acc0 = {0.f, 0.f, 0.f, 0.f};
        f32x4 acc1 = {0.f, 0.f, 0.f, 0.f};
#pragma unroll
        for (int kk = 0; kk < 4; ++kk) {
            bf16x8 b0 = *(const bf16x8*)(Bp0 + kk * 32);
            bf16x8 b1 = *(const bf16x8*)(Bp1 + kk * 32);
            acc0 = __builtin_amdgcn_mfma_f32_16x16x32_bf16(a0[kk], b0, acc0, 0, 0, 0);
            acc1 = __builtin_amdgcn_mfma_f32_16x16x32_bf16(a1[kk], b1, acc1, 0, 0, 0);
        }
        int c = c0 + m;                               // C/D layout: col=lane&15, row=quad*4+i
#pragma unroll
        for (int i = 0; i < 4; ++i) {
            int r = r0 + quad * 4 + i;
            if (r < N_NODES) {
                float* o = out + (size_t)r * 128 + c;
                float v = acc0[i] + acc1[i];
                if (mode == 0) *o = v;
                else           *o = *o + v + bias[c];
            }
        }
    }
}

extern "C" void kernel_launch(void* const* d_in, const int* in_sizes, int n_in,
                              void* d_out, int out_size, void* d_ws, size_t ws_size,
                              hipStream_t stream) {
    const float* x    = (const float*)d_in[0];
    const float* lap  = (const float*)d_in[1];
    const float* w    = (const float*)d_in[2];
    const float* bias = (const float*)d_in[3];
    const int*   ei   = (const int*)d_in[4];
    float* out = (float*)d_out;

    char* ws = (char*)d_ws;
    const size_t SZ_BF = (size_t)ROWS_PAD * 128 * 2;   // 25,608,192 B
    const size_t SZ_F8 = (size_t)ROWS_PAD * 128;       // 12,804,096 B
    // layout (lifetimes annotated):
    int2* ep            = (int2*)(ws);                              // [0, SZ_BF)
    unsigned char* xf8  = (unsigned char*)(ws + SZ_BF);             // dead after SpMM1
    unsigned char* t1_8 = (unsigned char*)(ws + SZ_BF + SZ_F8);     // dead after SpMM2
    unsigned char* t3_b = (unsigned char*)(ws + SZ_BF);             // reuses xf8+t1_8 region (bf16)
    unsigned char* t1_b = (unsigned char*)(ws + 2 * SZ_BF);
    unsigned char* t2_8 = (unsigned char*)(ws + 3 * SZ_BF);
    unsigned char* t2_b = (unsigned char*)(ws + 3 * SZ_BF + SZ_F8);
    uint2* ep_tmp       = (uint2*)(ws + 3 * SZ_BF);                 // aliases t2_8 + t2_b head; dead after rsort
    char* p = ws + 4 * SZ_BF + SZ_F8;
    int* rowstart = (int*)p; p += 400128;
    int* bcnt     = (int*)p; p += 3200;
    int* bbase    = (int*)p; p += 3200;
    int* bcursor  = (int*)p; p += 3200;
    unsigned short* wt = (unsigned short*)p;           // 4*128*128 bf16

    hipMemsetAsync(bcnt, 0, N_BUCKETS * sizeof(int), stream);
    k_convert_x<<<(ROWS_PAD * 64) / 256, 256, 0, stream>>>(x, (unsigned short*)xf8);
    k_convert_w<<<256, 256, 0, stream>>>(w, wt);
    k_bhist<<<(N_EDGES + 8191) / 8192, 256, 0, stream>>>(ei, bcnt);
    k_bscan<<<1, 1024, 0, stream>>>(bcnt, bbase, bcursor, rowstart);
    k_bin<<<(N_EDGES + 16383) / 16384, 1024, 0, stream>>>(ei, lap, bcursor, ep_tmp);
    k_rsort<<<N_BUCKETS, 256, 0, stream>>>(ep_tmp, bbase, rowstart, ep);

    // Tx1 = L x          (gather fp8 x; write bf16 + fp8)
    k_spmm8<<<ROWS_PAD / 4, 256, 0, stream>>>(xf8, nullptr, 0,
        (unsigned*)t1_8, (uint2*)t1_b, rowstart, ep, 1.f, 0.f);
    // out = x @ W0 + Tx1 @ W1    (x fp32 direct, Tx1 bf16)
    k_gemm2<<<ROWS_PAD / 64, 256, 0, stream>>>(x, 1, wt, t1_b, 0, wt + 16384, out, bias, 0);
    // Tx2 = 2 L Tx1 - x  (gather fp8 Tx1; z fp32 x; write bf16 + fp8)
    k_spmm8<<<ROWS_PAD / 4, 256, 0, stream>>>(t1_8, x, 3,
        (unsigned*)t2_8, (uint2*)t2_b, rowstart, ep, 2.f, -1.f);
    // Tx3 = 2 L Tx2 - Tx1 (gather fp8 Tx2; z bf16 Tx1; write bf16 only, into dead xf8/t1_8 region)
    k_spmm8<<<ROWS_PAD / 4, 256, 0, stream>>>(t2_8, t1_b, 1,
        nullptr, (uint2*)t3_b, rowstart, ep, 2.f, -1.f);
    // out += Tx2 @ W2 + Tx3 @ W3 + bias
    k_gemm2<<<ROWS_PAD / 64, 256, 0, stream>>>(t2_b, 0, wt + 2 * 16384, t3_b, 0, wt + 3 * 16384, out, bias, 1);
}